// Round 1
// baseline (2876.388 us; speedup 1.0000x reference)
//
#include <hip/hip_runtime.h>
#include <hip/hip_fp16.h>
#include <math.h>

#define HEADS  32
#define SEQ_Q  512
#define SEQ_KV 4096
#define D      128
#define TB     16    // tokens per prep block
#define QT     32    // attention q-tile
#define KT     128   // attention kv-tile

__device__ __forceinline__ float f16r(float x) {
    return __half2float(__float2half(x));   // emulate .astype(float16) round trip
}

// ---------------------------------------------------------------------------
// Key compression: Kext[token][0:128]   = unit_mse * f16(norm)        (k_mse)
//                  Kext[token][128:256] = sign * f16(res_norm) * corr
// grid: H*SKV/TB blocks, 128 threads
// ---------------------------------------------------------------------------
__global__ __launch_bounds__(128) void key_compress(
    const float* __restrict__ k, const float* __restrict__ R,
    const float* __restrict__ qjl, const float* __restrict__ kc,
    const float* __restrict__ kb, float* __restrict__ Kext)
{
    __shared__ float u[TB][132];   // unit vectors
    __shared__ float cb[TB][132];  // centroid values (rotated_mse)
    __shared__ float rb[TB][132];  // residual
    __shared__ float red[2 * TB];
    __shared__ float nrm[TB], invn[TB], hnrm[TB], rnrm[TB];

    const int j = threadIdx.x;            // 0..127 (dim index)
    const int base = blockIdx.x * TB;     // global token index

    float kreg[TB];
    #pragma unroll
    for (int t = 0; t < TB; ++t)
        kreg[t] = k[(size_t)(base + t) * D + j];

    // ---- norms (batched 2-wave reduction) ----
    float ss[TB];
    #pragma unroll
    for (int t = 0; t < TB; ++t) ss[t] = kreg[t] * kreg[t];
    #pragma unroll
    for (int o = 32; o > 0; o >>= 1) {
        #pragma unroll
        for (int t = 0; t < TB; ++t) ss[t] += __shfl_xor(ss[t], o, 64);
    }
    const int wid = j >> 6;
    if ((j & 63) == 0) {
        #pragma unroll
        for (int t = 0; t < TB; ++t) red[wid * TB + t] = ss[t];
    }
    __syncthreads();
    if (j < TB) {
        float n = sqrtf(red[j] + red[TB + j]);
        nrm[j] = n;
        invn[j] = 1.0f / (n + 1e-8f);
        hnrm[j] = f16r(n);
    }
    __syncthreads();

    #pragma unroll
    for (int t = 0; t < TB; ++t) u[t][j] = kreg[t] * invn[t];
    __syncthreads();

    // ---- rotated[t][j] = sum_d u[t][d] * R[j][d] ----
    float acc[TB];
    #pragma unroll
    for (int t = 0; t < TB; ++t) acc[t] = 0.f;
    const float* Rrow = R + (size_t)j * D;
    #pragma unroll 2
    for (int d = 0; d < D; d += 4) {
        float4 r4 = *reinterpret_cast<const float4*>(Rrow + d);
        #pragma unroll
        for (int t = 0; t < TB; ++t) {
            float4 u4 = *reinterpret_cast<const float4*>(&u[t][d]);
            acc[t] += u4.x * r4.x + u4.y * r4.y + u4.z * r4.z + u4.w * r4.w;
        }
    }

    // ---- quantize (searchsorted left: idx = count(b < x)) ----
    const float b0 = kb[0], b1 = kb[1], b2 = kb[2], b3 = kb[3],
                b4 = kb[4], b5 = kb[5], b6 = kb[6];
    #pragma unroll
    for (int t = 0; t < TB; ++t) {
        float x = acc[t];
        int idx = (x > b0) + (x > b1) + (x > b2) + (x > b3) +
                  (x > b4) + (x > b5) + (x > b6);
        cb[t][j] = kc[idx];
    }
    __syncthreads();

    // ---- unit_mse[t][d] = sum_j cb[t][j] * R[j][d]  (thread = d) ----
    float acc2[TB];
    #pragma unroll
    for (int t = 0; t < TB; ++t) acc2[t] = 0.f;
    #pragma unroll 2
    for (int jj = 0; jj < D; jj += 4) {
        float r0 = R[(size_t)(jj + 0) * D + j];
        float r1 = R[(size_t)(jj + 1) * D + j];
        float r2 = R[(size_t)(jj + 2) * D + j];
        float r3 = R[(size_t)(jj + 3) * D + j];
        #pragma unroll
        for (int t = 0; t < TB; ++t) {
            float4 c4 = *reinterpret_cast<const float4*>(&cb[t][jj]);
            acc2[t] += c4.x * r0 + c4.y * r1 + c4.z * r2 + c4.w * r3;
        }
    }

    // ---- residual (f32 norm), k_mse output (f16 norm) ----
    #pragma unroll
    for (int t = 0; t < TB; ++t) {
        float resid = kreg[t] - acc2[t] * nrm[t];
        rb[t][j] = resid;
        Kext[(size_t)(base + t) * 256 + j] = acc2[t] * hnrm[t];
        ss[t] = resid * resid;
    }
    #pragma unroll
    for (int o = 32; o > 0; o >>= 1) {
        #pragma unroll
        for (int t = 0; t < TB; ++t) ss[t] += __shfl_xor(ss[t], o, 64);
    }
    if ((j & 63) == 0) {
        #pragma unroll
        for (int t = 0; t < TB; ++t) red[wid * TB + t] = ss[t];
    }
    __syncthreads();
    if (j < TB) rnrm[j] = f16r(sqrtf(red[j] + red[TB + j]));
    __syncthreads();

    // ---- signs: inner[t][j] = sum_d rb[t][d] * qjl[j][d] ----
    const float corr = 1.25331413731550025f / 128.0f;  // sqrt(pi/2)/qjl_dim
    float acc3[TB];
    #pragma unroll
    for (int t = 0; t < TB; ++t) acc3[t] = 0.f;
    const float* Qr = qjl + (size_t)j * D;
    #pragma unroll 2
    for (int d = 0; d < D; d += 4) {
        float4 q4 = *reinterpret_cast<const float4*>(Qr + d);
        #pragma unroll
        for (int t = 0; t < TB; ++t) {
            float4 r4 = *reinterpret_cast<const float4*>(&rb[t][d]);
            acc3[t] += r4.x * q4.x + r4.y * q4.y + r4.z * q4.z + r4.w * q4.w;
        }
    }
    #pragma unroll
    for (int t = 0; t < TB; ++t) {
        float s = (acc3[t] >= 0.f) ? 1.f : -1.f;
        Kext[(size_t)(base + t) * 256 + 128 + j] = s * rnrm[t] * corr;
    }
}

// ---------------------------------------------------------------------------
// Value compression: Vapp[token][d] = (sum_j c[t][j]*Rv[j][d]) * f16(norm)
// ---------------------------------------------------------------------------
__global__ __launch_bounds__(128) void value_compress(
    const float* __restrict__ v, const float* __restrict__ Rv,
    const float* __restrict__ vc, const float* __restrict__ vb,
    float* __restrict__ Vapp)
{
    __shared__ float u[TB][132];
    __shared__ float cb[TB][132];
    __shared__ float red[2 * TB];
    __shared__ float nrm[TB], invn[TB], hnrm[TB];

    const int j = threadIdx.x;
    const int base = blockIdx.x * TB;

    float vreg[TB];
    #pragma unroll
    for (int t = 0; t < TB; ++t)
        vreg[t] = v[(size_t)(base + t) * D + j];

    float ss[TB];
    #pragma unroll
    for (int t = 0; t < TB; ++t) ss[t] = vreg[t] * vreg[t];
    #pragma unroll
    for (int o = 32; o > 0; o >>= 1) {
        #pragma unroll
        for (int t = 0; t < TB; ++t) ss[t] += __shfl_xor(ss[t], o, 64);
    }
    const int wid = j >> 6;
    if ((j & 63) == 0) {
        #pragma unroll
        for (int t = 0; t < TB; ++t) red[wid * TB + t] = ss[t];
    }
    __syncthreads();
    if (j < TB) {
        float n = sqrtf(red[j] + red[TB + j]);
        nrm[j] = n;
        invn[j] = 1.0f / (n + 1e-8f);
        hnrm[j] = f16r(n);
    }
    __syncthreads();

    #pragma unroll
    for (int t = 0; t < TB; ++t) u[t][j] = vreg[t] * invn[t];
    __syncthreads();

    float acc[TB];
    #pragma unroll
    for (int t = 0; t < TB; ++t) acc[t] = 0.f;
    const float* Rrow = Rv + (size_t)j * D;
    #pragma unroll 2
    for (int d = 0; d < D; d += 4) {
        float4 r4 = *reinterpret_cast<const float4*>(Rrow + d);
        #pragma unroll
        for (int t = 0; t < TB; ++t) {
            float4 u4 = *reinterpret_cast<const float4*>(&u[t][d]);
            acc[t] += u4.x * r4.x + u4.y * r4.y + u4.z * r4.z + u4.w * r4.w;
        }
    }

    float vbr[15];
    #pragma unroll
    for (int i = 0; i < 15; ++i) vbr[i] = vb[i];
    #pragma unroll
    for (int t = 0; t < TB; ++t) {
        float x = acc[t];
        int idx = 0;
        #pragma unroll
        for (int i = 0; i < 15; ++i) idx += (x > vbr[i]);
        cb[t][j] = vc[idx];
    }
    __syncthreads();

    float acc2[TB];
    #pragma unroll
    for (int t = 0; t < TB; ++t) acc2[t] = 0.f;
    #pragma unroll 2
    for (int jj = 0; jj < D; jj += 4) {
        float r0 = Rv[(size_t)(jj + 0) * D + j];
        float r1 = Rv[(size_t)(jj + 1) * D + j];
        float r2 = Rv[(size_t)(jj + 2) * D + j];
        float r3 = Rv[(size_t)(jj + 3) * D + j];
        #pragma unroll
        for (int t = 0; t < TB; ++t) {
            float4 c4 = *reinterpret_cast<const float4*>(&cb[t][jj]);
            acc2[t] += c4.x * r0 + c4.y * r1 + c4.z * r2 + c4.w * r3;
        }
    }
    #pragma unroll
    for (int t = 0; t < TB; ++t)
        Vapp[(size_t)(base + t) * D + j] = acc2[t] * hnrm[t];
}

// ---------------------------------------------------------------------------
// Q extension: Qext[token][0:128] = q, Qext[token][128:256] = q @ qjl^T
// ---------------------------------------------------------------------------
__global__ __launch_bounds__(128) void q_extend(
    const float* __restrict__ q, const float* __restrict__ qjl,
    float* __restrict__ Qext)
{
    __shared__ float u[TB][132];
    const int j = threadIdx.x;
    const int base = blockIdx.x * TB;

    #pragma unroll
    for (int t = 0; t < TB; ++t) {
        float val = q[(size_t)(base + t) * D + j];
        u[t][j] = val;
        Qext[(size_t)(base + t) * 256 + j] = val;
    }
    __syncthreads();

    float acc[TB];
    #pragma unroll
    for (int t = 0; t < TB; ++t) acc[t] = 0.f;
    const float* Qr = qjl + (size_t)j * D;
    #pragma unroll 2
    for (int d = 0; d < D; d += 4) {
        float4 q4 = *reinterpret_cast<const float4*>(Qr + d);
        #pragma unroll
        for (int t = 0; t < TB; ++t) {
            float4 u4 = *reinterpret_cast<const float4*>(&u[t][d]);
            acc[t] += u4.x * q4.x + u4.y * q4.y + u4.z * q4.z + u4.w * q4.w;
        }
    }
    #pragma unroll
    for (int t = 0; t < TB; ++t)
        Qext[(size_t)(base + t) * 256 + 128 + j] = acc[t];
}

// ---------------------------------------------------------------------------
// Flash attention over (Qext · Kext^T) * scaling, softmax, P · Vapp
// grid: (SQ/QT, H), 256 threads
// ---------------------------------------------------------------------------
__global__ __launch_bounds__(256) void attention(
    const float* __restrict__ Qext, const float* __restrict__ Kext,
    const float* __restrict__ Vapp, float* __restrict__ out)
{
    __shared__ float Qs[QT][260];
    __shared__ float Ps[QT][132];
    __shared__ float m_s[QT], l_s[QT], al_s[QT];

    const int tid = threadIdx.x;
    const int h = blockIdx.y;
    const int q0 = blockIdx.x * QT;
    const float scaling = 0.08838834764831845f;  // 1/sqrt(128)

    for (int idx = tid; idx < QT * 256; idx += 256) {
        int r = idx >> 8, c = idx & 255;
        Qs[r][c] = Qext[((size_t)h * SEQ_Q + q0 + r) * 256 + c];
    }
    if (tid < QT) { m_s[tid] = -INFINITY; l_s[tid] = 0.f; al_s[tid] = 0.f; }
    __syncthreads();

    const int rg = tid >> 5;   // 0..7 : 4 rows each
    const int cg = tid & 31;   // 0..31: 4 k-cols (S) / 4 d-cols (PV)

    float O[4][4];
    #pragma unroll
    for (int a = 0; a < 4; ++a)
        #pragma unroll
        for (int b = 0; b < 4; ++b) O[a][b] = 0.f;

    const float* Kh = Kext + (size_t)h * SEQ_KV * 256;
    const float* Vh = Vapp + (size_t)h * SEQ_KV * 128;

    for (int k0 = 0; k0 < SEQ_KV; k0 += KT) {
        // ---- S = Qext · Kext^T ----
        float S[4][4];
        #pragma unroll
        for (int a = 0; a < 4; ++a)
            #pragma unroll
            for (int b = 0; b < 4; ++b) S[a][b] = 0.f;

        const float* Kb = Kh + (size_t)k0 * 256;
        #pragma unroll 2
        for (int d = 0; d < 256; d += 4) {
            float4 q4[4], k4[4];
            #pragma unroll
            for (int i = 0; i < 4; ++i)
                q4[i] = *reinterpret_cast<const float4*>(&Qs[rg * 4 + i][d]);
            #pragma unroll
            for (int i = 0; i < 4; ++i)
                k4[i] = *reinterpret_cast<const float4*>(
                    Kb + (size_t)(cg * 4 + i) * 256 + d);
            #pragma unroll
            for (int a = 0; a < 4; ++a)
                #pragma unroll
                for (int b = 0; b < 4; ++b)
                    S[a][b] += q4[a].x * k4[b].x + q4[a].y * k4[b].y +
                               q4[a].z * k4[b].z + q4[a].w * k4[b].w;
        }

        // ---- online softmax row stats (row group is wave-local) ----
        #pragma unroll
        for (int a = 0; a < 4; ++a) {
            float rm = -INFINITY;
            #pragma unroll
            for (int b = 0; b < 4; ++b) {
                S[a][b] *= scaling;
                rm = fmaxf(rm, S[a][b]);
            }
            #pragma unroll
            for (int o = 16; o > 0; o >>= 1)
                rm = fmaxf(rm, __shfl_xor(rm, o, 64));
            int r = rg * 4 + a;
            float mold = m_s[r];          // wave-lockstep read before cg0 write
            float mn = fmaxf(mold, rm);
            float alpha = expf(mold - mn);  // -inf -> 0 on first tile
            float ps = 0.f;
            float pv[4];
            #pragma unroll
            for (int b = 0; b < 4; ++b) {
                float p = expf(S[a][b] - mn);
                pv[b] = p;
                ps += p;
            }
            #pragma unroll
            for (int o = 16; o > 0; o >>= 1)
                ps += __shfl_xor(ps, o, 64);
            if (cg == 0) {
                l_s[r] = l_s[r] * alpha + ps;
                m_s[r] = mn;
                al_s[r] = alpha;
            }
            #pragma unroll
            for (int b = 0; b < 4; ++b) Ps[r][cg * 4 + b] = pv[b];
        }
        __syncthreads();

        // ---- O = O*alpha + P · V ----
        #pragma unroll
        for (int a = 0; a < 4; ++a) {
            float alpha = al_s[rg * 4 + a];
            #pragma unroll
            for (int b = 0; b < 4; ++b) O[a][b] *= alpha;
        }
        const float* Vb = Vh + (size_t)k0 * 128;
        #pragma unroll 2
        for (int kk = 0; kk < KT; ++kk) {
            float4 v4 = *reinterpret_cast<const float4*>(
                Vb + (size_t)kk * 128 + cg * 4);
            #pragma unroll
            for (int a = 0; a < 4; ++a) {
                float p = Ps[rg * 4 + a][kk];
                O[a][0] += p * v4.x;
                O[a][1] += p * v4.y;
                O[a][2] += p * v4.z;
                O[a][3] += p * v4.w;
            }
        }
        __syncthreads();
    }

    // ---- epilogue ----
    #pragma unroll
    for (int a = 0; a < 4; ++a) {
        float inv = 1.0f / l_s[rg * 4 + a];
        float4 o4 = make_float4(O[a][0] * inv, O[a][1] * inv,
                                O[a][2] * inv, O[a][3] * inv);
        *reinterpret_cast<float4*>(
            out + ((size_t)h * SEQ_Q + q0 + rg * 4 + a) * 128 + cg * 4) = o4;
    }
}

extern "C" void kernel_launch(void* const* d_in, const int* in_sizes, int n_in,
                              void* d_out, int out_size, void* d_ws, size_t ws_size,
                              hipStream_t stream)
{
    const float* q   = (const float*)d_in[0];
    const float* k   = (const float*)d_in[1];
    const float* v   = (const float*)d_in[2];
    const float* Rk  = (const float*)d_in[3];
    const float* qjl = (const float*)d_in[4];
    const float* kc  = (const float*)d_in[5];
    const float* kb  = (const float*)d_in[6];
    const float* Rv  = (const float*)d_in[7];
    const float* vc  = (const float*)d_in[8];
    const float* vb  = (const float*)d_in[9];
    float* out = (float*)d_out;

    // workspace: Kext [H*SKV][256] | Vapp [H*SKV][128] | Qext [H*SQ][256]
    float* Kext = (float*)d_ws;
    float* Vapp = Kext + (size_t)HEADS * SEQ_KV * 256;
    float* Qext = Vapp + (size_t)HEADS * SEQ_KV * 128;

    key_compress<<<HEADS * SEQ_KV / TB, 128, 0, stream>>>(k, Rk, qjl, kc, kb, Kext);
    value_compress<<<HEADS * SEQ_KV / TB, 128, 0, stream>>>(v, Rv, vc, vb, Vapp);
    q_extend<<<HEADS * SEQ_Q / TB, 128, 0, stream>>>(q, qjl, Qext);
    attention<<<dim3(SEQ_Q / QT, HEADS), 256, 0, stream>>>(Qext, Kext, Vapp, out);
}

// Round 2
// 866.122 us; speedup vs baseline: 3.3210x; 3.3210x over previous
//
#include <hip/hip_runtime.h>
#include <hip/hip_fp16.h>
#include <hip/hip_bf16.h>
#include <math.h>

#define HEADS  32
#define SEQ_Q  512
#define SEQ_KV 4096
#define D      128
#define TB     16    // tokens per prep block

typedef __attribute__((ext_vector_type(8))) short short8v;
typedef __attribute__((ext_vector_type(4))) float f32x4;

__device__ __forceinline__ float f16r(float x) {
    return __half2float(__float2half(x));   // emulate .astype(float16) round trip
}
__device__ __forceinline__ ushort f2bf(float x) {
    __hip_bfloat16 b = __float2bfloat16(x);
    return __builtin_bit_cast(ushort, b);
}

// ---------------------------------------------------------------------------
// Key compression -> Kx bf16 [H*SKV][256]:
//   [0:128]   = unit_mse * f16(norm)            (k_mse)
//   [128:256] = sign * f16(res_norm) * corr
// ---------------------------------------------------------------------------
__global__ __launch_bounds__(128) void key_compress(
    const float* __restrict__ k, const float* __restrict__ R,
    const float* __restrict__ qjl, const float* __restrict__ kc,
    const float* __restrict__ kb, ushort* __restrict__ Kx)
{
    __shared__ float u[TB][132];
    __shared__ float cb[TB][132];
    __shared__ float rb[TB][132];
    __shared__ float red[2 * TB];
    __shared__ float nrm[TB], invn[TB], hnrm[TB], rnrm[TB];

    const int j = threadIdx.x;
    const int base = blockIdx.x * TB;

    float kreg[TB];
    #pragma unroll
    for (int t = 0; t < TB; ++t)
        kreg[t] = k[(size_t)(base + t) * D + j];

    float ss[TB];
    #pragma unroll
    for (int t = 0; t < TB; ++t) ss[t] = kreg[t] * kreg[t];
    #pragma unroll
    for (int o = 32; o > 0; o >>= 1) {
        #pragma unroll
        for (int t = 0; t < TB; ++t) ss[t] += __shfl_xor(ss[t], o, 64);
    }
    const int wid = j >> 6;
    if ((j & 63) == 0) {
        #pragma unroll
        for (int t = 0; t < TB; ++t) red[wid * TB + t] = ss[t];
    }
    __syncthreads();
    if (j < TB) {
        float n = sqrtf(red[j] + red[TB + j]);
        nrm[j] = n;
        invn[j] = 1.0f / (n + 1e-8f);
        hnrm[j] = f16r(n);
    }
    __syncthreads();

    #pragma unroll
    for (int t = 0; t < TB; ++t) u[t][j] = kreg[t] * invn[t];
    __syncthreads();

    float acc[TB];
    #pragma unroll
    for (int t = 0; t < TB; ++t) acc[t] = 0.f;
    const float* Rrow = R + (size_t)j * D;
    #pragma unroll 2
    for (int d = 0; d < D; d += 4) {
        float4 r4 = *reinterpret_cast<const float4*>(Rrow + d);
        #pragma unroll
        for (int t = 0; t < TB; ++t) {
            float4 u4 = *reinterpret_cast<const float4*>(&u[t][d]);
            acc[t] += u4.x * r4.x + u4.y * r4.y + u4.z * r4.z + u4.w * r4.w;
        }
    }

    const float b0 = kb[0], b1 = kb[1], b2 = kb[2], b3 = kb[3],
                b4 = kb[4], b5 = kb[5], b6 = kb[6];
    #pragma unroll
    for (int t = 0; t < TB; ++t) {
        float x = acc[t];
        int idx = (x > b0) + (x > b1) + (x > b2) + (x > b3) +
                  (x > b4) + (x > b5) + (x > b6);
        cb[t][j] = kc[idx];
    }
    __syncthreads();

    float acc2[TB];
    #pragma unroll
    for (int t = 0; t < TB; ++t) acc2[t] = 0.f;
    #pragma unroll 2
    for (int jj = 0; jj < D; jj += 4) {
        float r0 = R[(size_t)(jj + 0) * D + j];
        float r1 = R[(size_t)(jj + 1) * D + j];
        float r2 = R[(size_t)(jj + 2) * D + j];
        float r3 = R[(size_t)(jj + 3) * D + j];
        #pragma unroll
        for (int t = 0; t < TB; ++t) {
            float4 c4 = *reinterpret_cast<const float4*>(&cb[t][jj]);
            acc2[t] += c4.x * r0 + c4.y * r1 + c4.z * r2 + c4.w * r3;
        }
    }

    #pragma unroll
    for (int t = 0; t < TB; ++t) {
        float resid = kreg[t] - acc2[t] * nrm[t];
        rb[t][j] = resid;
        Kx[(size_t)(base + t) * 256 + j] = f2bf(acc2[t] * hnrm[t]);
        ss[t] = resid * resid;
    }
    #pragma unroll
    for (int o = 32; o > 0; o >>= 1) {
        #pragma unroll
        for (int t = 0; t < TB; ++t) ss[t] += __shfl_xor(ss[t], o, 64);
    }
    if ((j & 63) == 0) {
        #pragma unroll
        for (int t = 0; t < TB; ++t) red[wid * TB + t] = ss[t];
    }
    __syncthreads();
    if (j < TB) rnrm[j] = f16r(sqrtf(red[j] + red[TB + j]));
    __syncthreads();

    const float corr = 1.25331413731550025f / 128.0f;  // sqrt(pi/2)/qjl_dim
    float acc3[TB];
    #pragma unroll
    for (int t = 0; t < TB; ++t) acc3[t] = 0.f;
    const float* Qr = qjl + (size_t)j * D;
    #pragma unroll 2
    for (int d = 0; d < D; d += 4) {
        float4 q4 = *reinterpret_cast<const float4*>(Qr + d);
        #pragma unroll
        for (int t = 0; t < TB; ++t) {
            float4 r4 = *reinterpret_cast<const float4*>(&rb[t][d]);
            acc3[t] += r4.x * q4.x + r4.y * q4.y + r4.z * q4.z + r4.w * q4.w;
        }
    }
    #pragma unroll
    for (int t = 0; t < TB; ++t) {
        float s = (acc3[t] >= 0.f) ? 1.f : -1.f;
        Kx[(size_t)(base + t) * 256 + 128 + j] = f2bf(s * rnrm[t] * corr);
    }
}

// ---------------------------------------------------------------------------
// Value compression -> VT bf16 [H][128][SKV] (transposed for PV B-fragments)
// ---------------------------------------------------------------------------
__global__ __launch_bounds__(128) void value_compress(
    const float* __restrict__ v, const float* __restrict__ Rv,
    const float* __restrict__ vc, const float* __restrict__ vb,
    ushort* __restrict__ VTo)
{
    __shared__ float u[TB][132];
    __shared__ float cb[TB][132];
    __shared__ float red[2 * TB];
    __shared__ float nrm[TB], invn[TB], hnrm[TB];

    const int j = threadIdx.x;
    const int base = blockIdx.x * TB;

    float vreg[TB];
    #pragma unroll
    for (int t = 0; t < TB; ++t)
        vreg[t] = v[(size_t)(base + t) * D + j];

    float ss[TB];
    #pragma unroll
    for (int t = 0; t < TB; ++t) ss[t] = vreg[t] * vreg[t];
    #pragma unroll
    for (int o = 32; o > 0; o >>= 1) {
        #pragma unroll
        for (int t = 0; t < TB; ++t) ss[t] += __shfl_xor(ss[t], o, 64);
    }
    const int wid = j >> 6;
    if ((j & 63) == 0) {
        #pragma unroll
        for (int t = 0; t < TB; ++t) red[wid * TB + t] = ss[t];
    }
    __syncthreads();
    if (j < TB) {
        float n = sqrtf(red[j] + red[TB + j]);
        nrm[j] = n;
        invn[j] = 1.0f / (n + 1e-8f);
        hnrm[j] = f16r(n);
    }
    __syncthreads();

    #pragma unroll
    for (int t = 0; t < TB; ++t) u[t][j] = vreg[t] * invn[t];
    __syncthreads();

    float acc[TB];
    #pragma unroll
    for (int t = 0; t < TB; ++t) acc[t] = 0.f;
    const float* Rrow = Rv + (size_t)j * D;
    #pragma unroll 2
    for (int d = 0; d < D; d += 4) {
        float4 r4 = *reinterpret_cast<const float4*>(Rrow + d);
        #pragma unroll
        for (int t = 0; t < TB; ++t) {
            float4 u4 = *reinterpret_cast<const float4*>(&u[t][d]);
            acc[t] += u4.x * r4.x + u4.y * r4.y + u4.z * r4.z + u4.w * r4.w;
        }
    }

    float vbr[15];
    #pragma unroll
    for (int i = 0; i < 15; ++i) vbr[i] = vb[i];
    #pragma unroll
    for (int t = 0; t < TB; ++t) {
        float x = acc[t];
        int idx = 0;
        #pragma unroll
        for (int i = 0; i < 15; ++i) idx += (x > vbr[i]);
        cb[t][j] = vc[idx];
    }
    __syncthreads();

    float acc2[TB];
    #pragma unroll
    for (int t = 0; t < TB; ++t) acc2[t] = 0.f;
    #pragma unroll 2
    for (int jj = 0; jj < D; jj += 4) {
        float r0 = Rv[(size_t)(jj + 0) * D + j];
        float r1 = Rv[(size_t)(jj + 1) * D + j];
        float r2 = Rv[(size_t)(jj + 2) * D + j];
        float r3 = Rv[(size_t)(jj + 3) * D + j];
        #pragma unroll
        for (int t = 0; t < TB; ++t) {
            float4 c4 = *reinterpret_cast<const float4*>(&cb[t][jj]);
            acc2[t] += c4.x * r0 + c4.y * r1 + c4.z * r2 + c4.w * r3;
        }
    }

    // transposed bf16 write: VT[h][j][tok..tok+15] (32B contiguous per thread)
    const int hh = base >> 12;          // SEQ_KV = 4096
    const int tk = base & 4095;
    ushort tmp[TB];
    #pragma unroll
    for (int t = 0; t < TB; ++t) tmp[t] = f2bf(acc2[t] * hnrm[t]);
    uint pk[8];
    #pragma unroll
    for (int i = 0; i < 8; ++i)
        pk[i] = (uint)tmp[2 * i] | ((uint)tmp[2 * i + 1] << 16);
    ushort* dst = VTo + ((size_t)hh * 128 + j) * SEQ_KV + tk;
    *reinterpret_cast<uint4*>(dst)     = make_uint4(pk[0], pk[1], pk[2], pk[3]);
    *reinterpret_cast<uint4*>(dst + 8) = make_uint4(pk[4], pk[5], pk[6], pk[7]);
}

// ---------------------------------------------------------------------------
// Q extension -> Qx bf16 [H*SQ][256]: [0:128]=q, [128:256]=q@qjl^T
// ---------------------------------------------------------------------------
__global__ __launch_bounds__(128) void q_extend(
    const float* __restrict__ q, const float* __restrict__ qjl,
    ushort* __restrict__ Qxo)
{
    __shared__ float u[TB][132];
    const int j = threadIdx.x;
    const int base = blockIdx.x * TB;

    #pragma unroll
    for (int t = 0; t < TB; ++t) {
        float val = q[(size_t)(base + t) * D + j];
        u[t][j] = val;
        Qxo[(size_t)(base + t) * 256 + j] = f2bf(val);
    }
    __syncthreads();

    float acc[TB];
    #pragma unroll
    for (int t = 0; t < TB; ++t) acc[t] = 0.f;
    const float* Qr = qjl + (size_t)j * D;
    #pragma unroll 2
    for (int d = 0; d < D; d += 4) {
        float4 q4 = *reinterpret_cast<const float4*>(Qr + d);
        #pragma unroll
        for (int t = 0; t < TB; ++t) {
            float4 u4 = *reinterpret_cast<const float4*>(&u[t][d]);
            acc[t] += u4.x * q4.x + u4.y * q4.y + u4.z * q4.z + u4.w * q4.w;
        }
    }
    #pragma unroll
    for (int t = 0; t < TB; ++t)
        Qxo[(size_t)(base + t) * 256 + 128 + j] = f2bf(acc[t]);
}

// ---------------------------------------------------------------------------
// MFMA flash attention: 4 waves, QT=64 (16 q-rows/wave), KT=64
// grid: (HEADS, SEQ_Q/64)
// ---------------------------------------------------------------------------
__global__ __launch_bounds__(256) void attention(
    const ushort* __restrict__ Qx, const ushort* __restrict__ Kx,
    const ushort* __restrict__ VT, float* __restrict__ out)
{
    __shared__ ushort Ks[64][264];   // K tile, padded (528B row stride)
    __shared__ ushort Vs[128][72];   // V^T tile, padded (144B row stride)
    __shared__ ushort Ps[64][72];    // P (per-wave private 16-row slices)

    const int tid = threadIdx.x;
    const int h   = blockIdx.x;
    const int q0  = blockIdx.y * 64;
    const int w   = tid >> 6;
    const int l   = tid & 63;
    const int lr  = l & 15;
    const int lh  = l >> 4;
    const float scale = 0.08838834764831845f;  // 1/sqrt(128)

    // ---- Q fragments: register-cached for the whole kernel ----
    short8v qa[8];
    {
        const ushort* qrow = Qx + ((size_t)h * SEQ_Q + q0 + w * 16 + lr) * 256 + lh * 8;
        #pragma unroll
        for (int kk = 0; kk < 8; ++kk)
            qa[kk] = __builtin_bit_cast(short8v,
                *reinterpret_cast<const uint4*>(qrow + kk * 32));
    }

    const int krow = tid >> 5, kc16 = tid & 31;   // K staging: 8 rows x 32 chunks
    const int vrow = tid >> 3, vc8  = tid & 7;    // V staging: 32 rows x 8 chunks
    const ushort* Kg = Kx + (size_t)h * SEQ_KV * 256;
    const ushort* Vg = VT + (size_t)h * 128 * SEQ_KV;

    uint4 kst[8], vst[4];
    #pragma unroll
    for (int j = 0; j < 8; ++j)
        kst[j] = *reinterpret_cast<const uint4*>(
            Kg + (size_t)(krow + j * 8) * 256 + kc16 * 8);
    #pragma unroll
    for (int j = 0; j < 4; ++j)
        vst[j] = *reinterpret_cast<const uint4*>(
            Vg + (size_t)(vrow + j * 32) * SEQ_KV + vc8 * 8);

    f32x4 oacc[8];
    #pragma unroll
    for (int dc = 0; dc < 8; ++dc) oacc[dc] = (f32x4)(0.f);
    float mrow[4], lsum[4];
    #pragma unroll
    for (int r = 0; r < 4; ++r) { mrow[r] = -INFINITY; lsum[r] = 0.f; }

    for (int k0 = 0; k0 < SEQ_KV; k0 += 64) {
        __syncthreads();   // all waves done reading Ks/Vs of previous tile
        #pragma unroll
        for (int j = 0; j < 8; ++j)
            *reinterpret_cast<uint4*>(&Ks[krow + j * 8][kc16 * 8]) = kst[j];
        #pragma unroll
        for (int j = 0; j < 4; ++j)
            *reinterpret_cast<uint4*>(&Vs[vrow + j * 32][vc8 * 8]) = vst[j];

        if (k0 + 64 < SEQ_KV) {   // prefetch next tile into regs (hides HBM/L2)
            #pragma unroll
            for (int j = 0; j < 8; ++j)
                kst[j] = *reinterpret_cast<const uint4*>(
                    Kg + (size_t)(k0 + 64 + krow + j * 8) * 256 + kc16 * 8);
            #pragma unroll
            for (int j = 0; j < 4; ++j)
                vst[j] = *reinterpret_cast<const uint4*>(
                    Vg + (size_t)(vrow + j * 32) * SEQ_KV + k0 + 64 + vc8 * 8);
        }
        __syncthreads();   // staged tile visible

        // ---- S = Q · K^T (wave: 16 q-rows x 64 keys) ----
        f32x4 sacc[4];
        #pragma unroll
        for (int kc = 0; kc < 4; ++kc) sacc[kc] = (f32x4)(0.f);
        #pragma unroll
        for (int kk = 0; kk < 8; ++kk) {
            #pragma unroll
            for (int kc = 0; kc < 4; ++kc) {
                short8v b = *reinterpret_cast<const short8v*>(
                    &Ks[kc * 16 + lr][kk * 32 + lh * 8]);
                sacc[kc] = __builtin_amdgcn_mfma_f32_16x16x32_bf16(
                    qa[kk], b, sacc[kc], 0, 0, 0);
            }
        }

        // ---- online softmax (rows wave-local; C layout row = lh*4+r) ----
        #pragma unroll
        for (int r = 0; r < 4; ++r) {
            float mx = fmaxf(fmaxf(sacc[0][r], sacc[1][r]),
                             fmaxf(sacc[2][r], sacc[3][r]));
            #pragma unroll
            for (int off = 8; off > 0; off >>= 1)
                mx = fmaxf(mx, __shfl_xor(mx, off, 64));
            mx *= scale;
            float mn = fmaxf(mrow[r], mx);
            float alpha = __expf(mrow[r] - mn);
            float pv[4], ps = 0.f;
            #pragma unroll
            for (int kc = 0; kc < 4; ++kc) {
                float p = __expf(sacc[kc][r] * scale - mn);
                pv[kc] = p; ps += p;
            }
            #pragma unroll
            for (int off = 8; off > 0; off >>= 1)
                ps += __shfl_xor(ps, off, 64);
            lsum[r] = lsum[r] * alpha + ps;
            mrow[r] = mn;
            #pragma unroll
            for (int kc = 0; kc < 4; ++kc)
                Ps[w * 16 + lh * 4 + r][kc * 16 + lr] = f2bf(pv[kc]);
            #pragma unroll
            for (int dc = 0; dc < 8; ++dc)
                oacc[dc][r] *= alpha;
        }

        // ---- O += P · V ----
        #pragma unroll
        for (int kc2 = 0; kc2 < 2; ++kc2) {
            short8v pa = *reinterpret_cast<const short8v*>(
                &Ps[w * 16 + lr][kc2 * 32 + lh * 8]);
            #pragma unroll
            for (int dc = 0; dc < 8; ++dc) {
                short8v b = *reinterpret_cast<const short8v*>(
                    &Vs[dc * 16 + lr][kc2 * 32 + lh * 8]);
                oacc[dc] = __builtin_amdgcn_mfma_f32_16x16x32_bf16(
                    pa, b, oacc[dc], 0, 0, 0);
            }
        }
    }

    // ---- epilogue ----
    #pragma unroll
    for (int r = 0; r < 4; ++r) {
        float inv = 1.0f / lsum[r];
        float* orow = out + ((size_t)h * SEQ_Q + q0 + w * 16 + lh * 4 + r) * 128 + lr;
        #pragma unroll
        for (int dc = 0; dc < 8; ++dc)
            orow[dc * 16] = oacc[dc][r] * inv;
    }
}

extern "C" void kernel_launch(void* const* d_in, const int* in_sizes, int n_in,
                              void* d_out, int out_size, void* d_ws, size_t ws_size,
                              hipStream_t stream)
{
    const float* q   = (const float*)d_in[0];
    const float* k   = (const float*)d_in[1];
    const float* v   = (const float*)d_in[2];
    const float* Rk  = (const float*)d_in[3];
    const float* qjl = (const float*)d_in[4];
    const float* kc  = (const float*)d_in[5];
    const float* kb  = (const float*)d_in[6];
    const float* Rv  = (const float*)d_in[7];
    const float* vc  = (const float*)d_in[8];
    const float* vb  = (const float*)d_in[9];
    float* out = (float*)d_out;

    // workspace (bf16): Kx [H*SKV][256] | VT [H][128][SKV] | Qx [H*SQ][256]
    ushort* Kx  = (ushort*)d_ws;
    ushort* VTp = Kx + (size_t)HEADS * SEQ_KV * 256;
    ushort* Qx  = VTp + (size_t)HEADS * 128 * SEQ_KV;

    key_compress<<<HEADS * SEQ_KV / TB, 128, 0, stream>>>(k, Rk, qjl, kc, kb, Kx);
    value_compress<<<HEADS * SEQ_KV / TB, 128, 0, stream>>>(v, Rv, vc, vb, VTp);
    q_extend<<<HEADS * SEQ_Q / TB, 128, 0, stream>>>(q, qjl, Qx);
    attention<<<dim3(HEADS, SEQ_Q / 64), 256, 0, stream>>>(Qx, Kx, VTp, out);
}